// Round 9
// baseline (264.028 us; speedup 1.0000x reference)
//
#include <hip/hip_runtime.h>

#define N_NODES 100000
#define N_EDGES 3200000
#define IN_CH 24
#define HIDDEN 64
#define N_CLASSES 16

#define NBUCK 782       // ceil(N_NODES / 128), 128-node buckets
#define CAP 4608        // fixed bucket capacity: mean 4092, sigma 64 -> +8 sigma
#define PTBLOCKS 256
#define PTCHUNK 12500   // part: 256 * 12500 = E
#define NCASTB 1563     // ceil(N_NODES*16 / 1024)

typedef __attribute__((ext_vector_type(8))) short short8;
typedef __attribute__((ext_vector_type(4))) float float4_;
typedef __attribute__((ext_vector_type(2))) float float2v;
typedef __attribute__((ext_vector_type(4))) int int4v;
typedef __attribute__((ext_vector_type(2))) unsigned uint2v;

// raw buffer loads: 32-bit voffset addressing (1 VALU per gather addr),
// SRD in SGPRs, OOB (voffset >= num_records) returns 0 with no traffic.
__device__ unsigned llvm_amdgcn_raw_buffer_load_u32(int4v, int, int, int) __asm("llvm.amdgcn.raw.buffer.load.i32");
__device__ uint2v llvm_amdgcn_raw_buffer_load_u32x2(int4v, int, int, int) __asm("llvm.amdgcn.raw.buffer.load.v2i32");

__device__ __forceinline__ int4v make_srd(const void* p, unsigned bytes) {
    unsigned long long a = (unsigned long long)p;
    int4v r;
    r.x = (int)(unsigned)a;
    r.y = (int)((unsigned)(a >> 32) & 0xFFFFu);  // stride=0, flags=0
    r.z = (int)bytes;                            // num_records in bytes
    r.w = 0x00020000;                            // raw dword access
    return r;
}

__device__ __forceinline__ unsigned short f2bf(float f) {
    union { float f; unsigned int u; } v; v.f = f;
    unsigned int u = v.u;
    return (unsigned short)((u + 0x7FFFu + ((u >> 16) & 1u)) >> 16);
}
// packed f32x2 -> bf16x2 (RNE, matches f2bf) in 1 instruction
__device__ __forceinline__ unsigned cvt_pk_bf16(float a, float b) {
    unsigned r;
    asm("v_cvt_pk_bf16_f32 %0, %1, %2" : "=v"(r) : "v"(a), "v"(b));
    return r;
}
// fp8 e4m3 (OCP on gfx950) pack/unpack via HW converts
__device__ __forceinline__ unsigned short pk_fp8(float a, float b) {
    return (unsigned short)(__builtin_amdgcn_cvt_pk_fp8_f32(a, b, 0, false) & 0xFFFF);
}
// accumulate one dword = 4 fp8 into A[0..1] (float2 pairs; v_pk_add_f32)
__device__ __forceinline__ void accum_dw(float2v* A, unsigned w) {
    A[0] += __builtin_amdgcn_cvt_pk_f32_fp8(w, false);
    A[1] += __builtin_amdgcn_cvt_pk_f32_fp8(w, true);
}
__device__ __forceinline__ short8 mk8(unsigned d0, unsigned d1, unsigned d2, unsigned d3) {
    union { unsigned u[4]; short8 s; } v;
    v.u[0] = d0; v.u[1] = d1; v.u[2] = d2; v.u[3] = d3;
    return v.s;
}

// ---------------- merged: bucket partition | x cast | weight prep ----------
// blocks [0,PTBLOCKS): edge partition; [PTBLOCKS,PTBLOCKS+NCASTB): castx;
// last block: weight prep. Independent work overlapped in one launch.

__global__ __launch_bounds__(1024) void k_partx(const int* __restrict__ src,
                                                const int* __restrict__ dst,
                                                int* __restrict__ bucketFill,
                                                unsigned int* __restrict__ pedges,
                                                const float* __restrict__ x,
                                                unsigned short* __restrict__ X8s,
                                                const float* __restrict__ W1l,
                                                const float* __restrict__ W1r,
                                                const float* __restrict__ W2l,
                                                const float* __restrict__ W2r,
                                                const float* __restrict__ Wc,
                                                const float* __restrict__ b2,
                                                const float* __restrict__ bc,
                                                unsigned short* __restrict__ Bt1,
                                                unsigned short* __restrict__ Bt2,
                                                float* __restrict__ bias2) {
    __shared__ int cntL[NBUCK];
    __shared__ int baseL[NBUCK];
    int t = threadIdx.x;
    int bid = blockIdx.x;
    if (bid >= PTBLOCKS) {
        if (bid < PTBLOCKS + NCASTB) {
            // ---- castx: x fp32 -> X8 fp8 rows (32B: 24 real + 8 zero pad) ----
            int gid = (bid - PTBLOCKS) * 1024 + t;
            if (gid >= N_NODES * 16) return;
            int n = gid >> 4, kp = gid & 15;
            if (kp < 12) {
                const float2 v = *(const float2*)(x + n * 24 + kp * 2);
                X8s[n * 16 + kp] = pk_fp8(v.x, v.y);
            } else {
                X8s[n * 16 + kp] = 0;
            }
        } else {
            // ---- weight prep ----
            for (int i = t; i < 64 * 64; i += 1024) {
                int o = i >> 6, k = i & 63;
                float v = (k < 24) ? W1r[o * 24 + k]
                                   : ((k < 48) ? W1l[o * 24 + k - 24] : 0.f);
                Bt1[i] = f2bf(v);
            }
            for (int i = t; i < 64 * 128; i += 1024) {
                int o = i >> 7, k = i & 127;
                float v = (k < 64) ? W2l[o * 64 + k] : W2r[o * 64 + k - 64];
                Bt2[i] = f2bf(v);
            }
            for (int i = t; i < 16 * 128; i += 1024) {
                int c = i >> 7, k = i & 127;
                const float* M = (k < 64) ? W2l : W2r;
                int kk = k & 63;
                float s = 0.f;
                for (int j = 0; j < 64; j++) s += Wc[c * 64 + j] * M[j * 64 + kk];
                Bt2[(64 + c) * 128 + k] = f2bf(s);
            }
            for (int i = t; i < 80; i += 1024) {
                if (i < 64) bias2[i] = b2[i];
                else {
                    int c = i - 64;
                    float s = bc[c];
                    for (int j = 0; j < 64; j++) s += Wc[c * 64 + j] * b2[j];
                    bias2[i] = s;
                }
            }
        }
        return;
    }
    // ---- edge partition ----
    int cbeg = bid * PTCHUNK;
    int d[13], s[13];
#pragma unroll
    for (int k = 0; k < 13; k++) {
        int o = k * 1024 + t;
        bool ok = o < PTCHUNK;
        d[k] = ok ? dst[cbeg + o] : -1;
        s[k] = ok ? src[cbeg + o] : 0;
    }
    for (int i = t; i < NBUCK; i += 1024) cntL[i] = 0;
    __syncthreads();
#pragma unroll
    for (int k = 0; k < 13; k++)
        if (d[k] >= 0) atomicAdd(&cntL[d[k] >> 7], 1);
    __syncthreads();
    for (int i = t; i < NBUCK; i += 1024) {
        int c = cntL[i];
        if (c) baseL[i] = i * CAP + atomicAdd(&bucketFill[i], c);
        cntL[i] = 0;
    }
    __syncthreads();
#pragma unroll
    for (int k = 0; k < 13; k++)
        if (d[k] >= 0) {
            int bk = d[k] >> 7;
            int r = atomicAdd(&cntL[bk], 1);
            pedges[baseL[bk] + r] = ((unsigned int)(d[k] & 127) << 17) | (unsigned int)s[k];
        }
}

// per-bucket finalize: sorted srcs + per-node (beg,end). int LDS atomics only
// (FLOAT LDS atomics are catastrophic on gfx950 — R9: 29x regression)
__global__ __launch_bounds__(1024) void k_bucket(const unsigned int* __restrict__ pedges,
                                                 const int* __restrict__ bucketFill,
                                                 int2* __restrict__ begend,
                                                 int* __restrict__ srcs, int N) {
    __shared__ int ncnt[128];
    __shared__ int sps[128];
    int b = blockIdx.x;
    int t = threadIdx.x;
    int eb0 = b * CAP;
    int m = bucketFill[b];
    unsigned int v[5];
#pragma unroll
    for (int k = 0; k < 5; k++) {
        int o = k * 1024 + t;
        v[k] = (o < m) ? pedges[eb0 + o] : 0xFFFFFFFFu;
    }
    if (t < 128) ncnt[t] = 0;
    __syncthreads();
#pragma unroll
    for (int k = 0; k < 5; k++)
        if (v[k] != 0xFFFFFFFFu) atomicAdd(&ncnt[v[k] >> 17], 1);
    __syncthreads();
    int myc = (t < 128) ? ncnt[t] : 0;
    int val = myc;
    if (t < 128) sps[t] = val;
    __syncthreads();
    for (int off = 1; off < 128; off <<= 1) {
        int vv = (t >= off && t < 128) ? sps[t - off] : 0;
        __syncthreads();
        if (t < 128) { val += vv; sps[t] = val; }
        __syncthreads();
    }
    int mybase = val - myc;
    int node = b * 128 + t;
    if (t < 128 && node < N) {
        int2 be; be.x = eb0 + mybase; be.y = eb0 + mybase + myc;
        begend[node] = be;
    }
    if (t < 128) { sps[t] = mybase; ncnt[t] = 0; }
    // zero slack tail so masked tail gathers read node 0 (cnt+32 <= CAP)
    if (t < 32) srcs[eb0 + m + t] = 0;
    __syncthreads();
#pragma unroll
    for (int k = 0; k < 5; k++)
        if (v[k] != 0xFFFFFFFFu) {
            unsigned int nl = v[k] >> 17;
            int r = atomicAdd(&ncnt[nl], 1);
            srcs[eb0 + sps[nl] + r] = (int)(v[k] & 0x1FFFF);
        }
}

// ---------------- fused layer kernels ----------------
// Block = 128 thr = 2 INDEPENDENT waves; each wave owns its own 16-node
// strip (grid N/32). Per wave: aggregate 16 nodes (r1 loop, identical
// numerics) -> per-wave LDS slab (wave-synchronous LDS: same-wave write->
// read needs no barrier), then compute all GEMM tiles for the strip.
// Zero __syncthreads: no barrier imbalance; 2-wave blocks keep the
// 16-workgroup/CU x 2 = 32-wave occupancy ceiling.

// K1: agg1 (X8 gather) + gemm1 -> A2 h-zone bf16 + H8 fp8
__global__ __launch_bounds__(128) void k_fuse1(const float* __restrict__ x,
                                               const unsigned int* __restrict__ X8u,
                                               const int2* __restrict__ begend,
                                               const int* __restrict__ srcs,
                                               const unsigned short* __restrict__ Bt1,
                                               const float* __restrict__ b1,
                                               unsigned short* __restrict__ A2s,
                                               unsigned char* __restrict__ H8b) {
    __shared__ unsigned int lds_mean[2][16][20];   // per-wave slab; stride 20 dw
    int w = threadIdx.x >> 6;
    int lane = threadIdx.x & 63;
    int base = blockIdx.x * 32 + w * 16;   // this wave's strip
    int grp = lane >> 3;    // 0..7 edge slot
    int sub = lane & 7;     // dword of 32B row
    const int4v srdX = make_srd(X8u, N_NODES * 32u);
    const int4v srdS = make_srd(srcs, (unsigned)NBUCK * CAP * 4u);
    int suboff = sub * 4;

    // ---- phase 1: this wave aggregates its 16 nodes ----
    for (int i = 0; i < 16; i++) {
        int2 be = begend[base + i];
        int b = be.x, e = be.y;
        float2v A[2] = {{0.f, 0.f}, {0.f, 0.f}};
        int nfull = (e - b) & ~31;
        int j = b;
        int vo = (b + grp) * 4;
        for (; j < b + nfull; j += 32, vo += 128) {
            int s0 = (int)llvm_amdgcn_raw_buffer_load_u32(srdS, vo, 0, 0);
            int s1 = (int)llvm_amdgcn_raw_buffer_load_u32(srdS, vo + 32, 0, 0);
            int s2 = (int)llvm_amdgcn_raw_buffer_load_u32(srdS, vo + 64, 0, 0);
            int s3 = (int)llvm_amdgcn_raw_buffer_load_u32(srdS, vo + 96, 0, 0);
            unsigned u0 = llvm_amdgcn_raw_buffer_load_u32(srdX, (s0 << 5) + suboff, 0, 0);
            unsigned u1 = llvm_amdgcn_raw_buffer_load_u32(srdX, (s1 << 5) + suboff, 0, 0);
            unsigned u2 = llvm_amdgcn_raw_buffer_load_u32(srdX, (s2 << 5) + suboff, 0, 0);
            unsigned u3 = llvm_amdgcn_raw_buffer_load_u32(srdX, (s3 << 5) + suboff, 0, 0);
            accum_dw(A, u0); accum_dw(A, u1); accum_dw(A, u2); accum_dw(A, u3);
        }
        if (j < e) {
            int j0 = j + grp;
            int s0 = (int)llvm_amdgcn_raw_buffer_load_u32(srdS, vo, 0, 0);
            int s1 = (int)llvm_amdgcn_raw_buffer_load_u32(srdS, vo + 32, 0, 0);
            int s2 = (int)llvm_amdgcn_raw_buffer_load_u32(srdS, vo + 64, 0, 0);
            int s3 = (int)llvm_amdgcn_raw_buffer_load_u32(srdS, vo + 96, 0, 0);
            int o0 = (j0 < e)      ? ((s0 << 5) + suboff) : 0x7FFF0000;
            int o1 = (j0 + 8 < e)  ? ((s1 << 5) + suboff) : 0x7FFF0000;
            int o2 = (j0 + 16 < e) ? ((s2 << 5) + suboff) : 0x7FFF0000;
            int o3 = (j0 + 24 < e) ? ((s3 << 5) + suboff) : 0x7FFF0000;
            unsigned u0 = llvm_amdgcn_raw_buffer_load_u32(srdX, o0, 0, 0);
            unsigned u1 = llvm_amdgcn_raw_buffer_load_u32(srdX, o1, 0, 0);
            unsigned u2 = llvm_amdgcn_raw_buffer_load_u32(srdX, o2, 0, 0);
            unsigned u3 = llvm_amdgcn_raw_buffer_load_u32(srdX, o3, 0, 0);
            accum_dw(A, u0); accum_dw(A, u1); accum_dw(A, u2); accum_dw(A, u3);
        }
#pragma unroll
        for (int mm = 8; mm <= 32; mm <<= 1) {
#pragma unroll
            for (int q = 0; q < 2; q++) {
                float2v t;
                t.x = __shfl_xor(A[q].x, mm, 64);
                t.y = __shfl_xor(A[q].y, mm, 64);
                A[q] += t;
            }
        }
        if (lane < 8) {
            // feats 4*sub..4*sub+3 -> mean dwords 2*sub, 2*sub+1
            float inv = __builtin_amdgcn_rcpf((float)max(e - b, 1));
            lds_mean[w][i][sub * 2]     = cvt_pk_bf16(A[0].x * inv, A[0].y * inv);
            lds_mean[w][i][sub * 2 + 1] = cvt_pk_bf16(A[1].x * inv, A[1].y * inv);
        }
    }
    // no barrier: same-wave LDS write->read (wave-synchronous, lgkmcnt-ordered)

    // ---- phase 2: this wave computes all 4 tiles (A-frags built once) ----
    int m = lane & 15, quad = lane >> 4;
    int row = base + m;
    // A-vector (64 shorts): [x bf16 0..23 | mean 0..23 | zeros]
    short8 a0, a1;
    if (quad < 3) {   // shorts quad*8..+7 = x feats quad*8..+7
        const float4* xp = (const float4*)(x + row * 24 + quad * 8);
        float4 v0 = xp[0], v1 = xp[1];
        a0 = mk8(cvt_pk_bf16(v0.x, v0.y), cvt_pk_bf16(v0.z, v0.w),
                 cvt_pk_bf16(v1.x, v1.y), cvt_pk_bf16(v1.z, v1.w));
    } else {          // shorts 24..31 = mean feats 0..7 = lds dwords 0..3
        a0 = *(const short8*)&lds_mean[w][m][0];
    }
    if (quad == 0)      a1 = *(const short8*)&lds_mean[w][m][4];  // mean 8-15
    else if (quad == 1) a1 = *(const short8*)&lds_mean[w][m][8];  // mean 16-23
    else                a1 = mk8(0u, 0u, 0u, 0u);                 // k 48-63 zeros
#pragma unroll
    for (int t = 0; t < 4; t++) {
        short8 bf0 = *(const short8*)(Bt1 + (t * 16 + m) * 64 + quad * 8);
        short8 bf1 = *(const short8*)(Bt1 + (t * 16 + m) * 64 + 32 + quad * 8);
        float bias = b1[t * 16 + m];
        float4_ c = {0.f, 0.f, 0.f, 0.f};
        c = __builtin_amdgcn_mfma_f32_16x16x32_bf16(a0, bf0, c, 0, 0, 0);
        c = __builtin_amdgcn_mfma_f32_16x16x32_bf16(a1, bf1, c, 0, 0, 0);
        int col = t * 16 + m;
#pragma unroll
        for (int r = 0; r < 4; r++) {
            int row2 = base + quad * 4 + r;
            float v = fmaxf(c[r] + bias, 0.f);
            A2s[row2 * 128 + 64 + col] = f2bf(v);
            H8b[row2 * 64 + col] =
                (unsigned char)(__builtin_amdgcn_cvt_pk_fp8_f32(v, 0.f, 0, false) & 0xFF);
        }
    }
}

// K2: agg2 (H8 gather) + gemm2 -> embeddings f32 (overwrites A2 rows) + logits
__global__ __launch_bounds__(128) void k_fuse2(const unsigned int* __restrict__ H8u,
                                               const int2* __restrict__ begend,
                                               const int* __restrict__ srcs,
                                               const unsigned short* __restrict__ Bt2,
                                               const float* __restrict__ bias2,
                                               unsigned short* A2s,
                                               float* __restrict__ logits) {
    __shared__ unsigned int lds_h[2][16][36];      // per-wave slab; stride 36 dw
    int w = threadIdx.x >> 6;
    int lane = threadIdx.x & 63;
    int base = blockIdx.x * 32 + w * 16;   // this wave's strip
    int grp = lane >> 3;    // 0..7 edge slot
    int sub = lane & 7;     // 8B chunk of 64B row
    const int4v srdH = make_srd(H8u, N_NODES * 64u);
    const int4v srdS = make_srd(srcs, (unsigned)NBUCK * CAP * 4u);
    int suboff = sub * 8;

    // ---- phase 1: this wave aggregates its 16 nodes ----
    for (int i = 0; i < 16; i++) {
        int2 be = begend[base + i];
        int b = be.x, e = be.y;
        float2v A[4] = {{0.f, 0.f}, {0.f, 0.f}, {0.f, 0.f}, {0.f, 0.f}};
        int nfull = (e - b) & ~31;
        int j = b;
        int vo = (b + grp) * 4;
        for (; j < b + nfull; j += 32, vo += 128) {
            int s0 = (int)llvm_amdgcn_raw_buffer_load_u32(srdS, vo, 0, 0);
            int s1 = (int)llvm_amdgcn_raw_buffer_load_u32(srdS, vo + 32, 0, 0);
            int s2 = (int)llvm_amdgcn_raw_buffer_load_u32(srdS, vo + 64, 0, 0);
            int s3 = (int)llvm_amdgcn_raw_buffer_load_u32(srdS, vo + 96, 0, 0);
            uint2v u0 = llvm_amdgcn_raw_buffer_load_u32x2(srdH, (s0 << 6) + suboff, 0, 0);
            uint2v u1 = llvm_amdgcn_raw_buffer_load_u32x2(srdH, (s1 << 6) + suboff, 0, 0);
            uint2v u2 = llvm_amdgcn_raw_buffer_load_u32x2(srdH, (s2 << 6) + suboff, 0, 0);
            uint2v u3 = llvm_amdgcn_raw_buffer_load_u32x2(srdH, (s3 << 6) + suboff, 0, 0);
            accum_dw(A, u0.x); accum_dw(A + 2, u0.y);
            accum_dw(A, u1.x); accum_dw(A + 2, u1.y);
            accum_dw(A, u2.x); accum_dw(A + 2, u2.y);
            accum_dw(A, u3.x); accum_dw(A + 2, u3.y);
        }
        if (j < e) {
            int j0 = j + grp;
            int s0 = (int)llvm_amdgcn_raw_buffer_load_u32(srdS, vo, 0, 0);
            int s1 = (int)llvm_amdgcn_raw_buffer_load_u32(srdS, vo + 32, 0, 0);
            int s2 = (int)llvm_amdgcn_raw_buffer_load_u32(srdS, vo + 64, 0, 0);
            int s3 = (int)llvm_amdgcn_raw_buffer_load_u32(srdS, vo + 96, 0, 0);
            int o0 = (j0 < e)      ? ((s0 << 6) + suboff) : 0x7FFF0000;
            int o1 = (j0 + 8 < e)  ? ((s1 << 6) + suboff) : 0x7FFF0000;
            int o2 = (j0 + 16 < e) ? ((s2 << 6) + suboff) : 0x7FFF0000;
            int o3 = (j0 + 24 < e) ? ((s3 << 6) + suboff) : 0x7FFF0000;
            uint2v u0 = llvm_amdgcn_raw_buffer_load_u32x2(srdH, o0, 0, 0);
            uint2v u1 = llvm_amdgcn_raw_buffer_load_u32x2(srdH, o1, 0, 0);
            uint2v u2 = llvm_amdgcn_raw_buffer_load_u32x2(srdH, o2, 0, 0);
            uint2v u3 = llvm_amdgcn_raw_buffer_load_u32x2(srdH, o3, 0, 0);
            accum_dw(A, u0.x); accum_dw(A + 2, u0.y);
            accum_dw(A, u1.x); accum_dw(A + 2, u1.y);
            accum_dw(A, u2.x); accum_dw(A + 2, u2.y);
            accum_dw(A, u3.x); accum_dw(A + 2, u3.y);
        }
#pragma unroll
        for (int mm = 8; mm <= 32; mm <<= 1) {
#pragma unroll
            for (int q = 0; q < 4; q++) {
                float2v t;
                t.x = __shfl_xor(A[q].x, mm, 64);
                t.y = __shfl_xor(A[q].y, mm, 64);
                A[q] += t;
            }
        }
        if (lane < 8) {
            // feats 8*sub..8*sub+7 -> mean dwords 4*sub..4*sub+3
            float inv = __builtin_amdgcn_rcpf((float)max(e - b, 1));
            uint4 o;
            o.x = cvt_pk_bf16(A[0].x * inv, A[0].y * inv);
            o.y = cvt_pk_bf16(A[1].x * inv, A[1].y * inv);
            o.z = cvt_pk_bf16(A[2].x * inv, A[2].y * inv);
            o.w = cvt_pk_bf16(A[3].x * inv, A[3].y * inv);
            *(uint4*)&lds_h[w][i][sub * 4] = o;
        }
    }
    // no barrier: same-wave LDS write->read; h-zone read/overwrite is also
    // same-wave (this wave owns rows base..base+15 for reads AND writes)

    // ---- phase 2: this wave computes tiles 0..3 + logits for its strip ----
    int m = lane & 15, quad = lane >> 4;
    int row = base + m;
    // h-zone A-frags loaded into registers BEFORE the overwrite loop
    short8 a2 = *(const short8*)(A2s + row * 128 + 64 + quad * 8);
    short8 a3 = *(const short8*)(A2s + row * 128 + 96 + quad * 8);
    short8 a0 = *(const short8*)&lds_h[w][m][quad * 4];
    short8 a1 = *(const short8*)&lds_h[w][m][16 + quad * 4];
#pragma unroll
    for (int t = 0; t < 5; t++) {
        int trow = ((t < 4) ? t * 16 : 64) + m;
        short8 bf0 = *(const short8*)(Bt2 + trow * 128 + quad * 8);
        short8 bf1 = *(const short8*)(Bt2 + trow * 128 + 32 + quad * 8);
        short8 bf2 = *(const short8*)(Bt2 + trow * 128 + 64 + quad * 8);
        short8 bf3 = *(const short8*)(Bt2 + trow * 128 + 96 + quad * 8);
        float bias = bias2[trow];
        float4_ c = {0.f, 0.f, 0.f, 0.f};
        c = __builtin_amdgcn_mfma_f32_16x16x32_bf16(a0, bf0, c, 0, 0, 0);
        c = __builtin_amdgcn_mfma_f32_16x16x32_bf16(a1, bf1, c, 0, 0, 0);
        c = __builtin_amdgcn_mfma_f32_16x16x32_bf16(a2, bf2, c, 0, 0, 0);
        c = __builtin_amdgcn_mfma_f32_16x16x32_bf16(a3, bf3, c, 0, 0, 0);
        if (t < 4) {
            float* embp = (float*)A2s;
            int col = t * 16 + m;
#pragma unroll
            for (int r = 0; r < 4; r++) {
                int row2 = base + quad * 4 + r;
                embp[row2 * 64 + col] = c[r] + bias;
            }
        } else {
#pragma unroll
            for (int r = 0; r < 4; r++) {
                int row2 = base + quad * 4 + r;
                logits[row2 * 16 + m] = c[r] + bias;
            }
        }
    }
}

// ---------------- launch ----------------

extern "C" void kernel_launch(void* const* d_in, const int* in_sizes, int n_in,
                              void* d_out, int out_size, void* d_ws, size_t ws_size,
                              hipStream_t stream) {
    const float* x = (const float*)d_in[0];
    const int* edge = (const int*)d_in[1];
    const int* srcIdx = edge;
    const int* dstIdx = edge + N_EDGES;
    const float* W1l = (const float*)d_in[2];
    const float* b1  = (const float*)d_in[3];
    const float* W1r = (const float*)d_in[4];
    const float* W2l = (const float*)d_in[5];
    const float* b2  = (const float*)d_in[6];
    const float* W2r = (const float*)d_in[7];
    const float* Wc  = (const float*)d_in[8];
    const float* bc  = (const float*)d_in[9];

    float* logits = (float*)d_out;
    unsigned short* A2s = (unsigned short*)((float*)d_out + (size_t)N_NODES * N_CLASSES);

    char* w = (char*)d_ws;
    auto carve = [&](size_t bytes) {
        char* p = w;
        w += (bytes + 255) & ~(size_t)255;
        return p;
    };
    int2* begend         = (int2*)carve((size_t)N_NODES * sizeof(int2));
    int* srcs            = (int*)carve((size_t)NBUCK * CAP * sizeof(int));
    unsigned int* pedges = (unsigned int*)carve((size_t)NBUCK * CAP * sizeof(unsigned int));
    unsigned short* X8s  = (unsigned short*)carve((size_t)N_NODES * 32);   // fp8 x, 32B rows
    unsigned char* H8b   = (unsigned char*)carve((size_t)N_NODES * 64);    // fp8 h, 64B rows
    int* bucketFill      = (int*)carve(NBUCK * sizeof(int));
    unsigned short* Bt1  = (unsigned short*)carve(64 * 64 * sizeof(unsigned short));
    unsigned short* Bt2  = (unsigned short*)carve(80 * 128 * sizeof(unsigned short));
    float* bias2         = (float*)carve(80 * sizeof(float));

    unsigned int* X8u = (unsigned int*)X8s;
    unsigned int* H8u = (unsigned int*)H8b;

    hipMemsetAsync(bucketFill, 0, NBUCK * sizeof(int), stream);
    k_partx<<<PTBLOCKS + NCASTB + 1, 1024, 0, stream>>>(
        srcIdx, dstIdx, bucketFill, pedges, x, X8s,
        W1l, W1r, W2l, W2r, Wc, b2, bc, Bt1, Bt2, bias2);
    k_bucket<<<NBUCK, 1024, 0, stream>>>(pedges, bucketFill, begend, srcs, N_NODES);

    int fgrid = N_NODES / 32;   // 3125 blocks x 2 independent wave-strips
    k_fuse1<<<fgrid, 128, 0, stream>>>(x, X8u, begend, srcs, Bt1, b1, A2s, H8b);
    k_fuse2<<<fgrid, 128, 0, stream>>>(H8u, begend, srcs, Bt2, bias2, A2s, logits);
}

// Round 11
// 246.141 us; speedup vs baseline: 1.0727x; 1.0727x over previous
//
#include <hip/hip_runtime.h>

#define N_NODES 100000
#define N_EDGES 3200000
#define IN_CH 24
#define HIDDEN 64
#define N_CLASSES 16

#define NBUCK 782       // ceil(N_NODES / 128), 128-node buckets
#define CAP 4608        // fixed bucket capacity: mean 4092, sigma 64 -> +8 sigma
#define PTBLOCKS 256
#define PTCHUNK 12500   // part: 256 * 12500 = E
#define NCASTB 1563     // ceil(N_NODES*16 / 1024)

typedef __attribute__((ext_vector_type(8))) short short8;
typedef __attribute__((ext_vector_type(4))) float float4_;
typedef __attribute__((ext_vector_type(2))) float float2v;
typedef __attribute__((ext_vector_type(4))) int int4v;
typedef __attribute__((ext_vector_type(2))) unsigned uint2v;

// raw buffer loads: 32-bit voffset addressing (1 VALU per gather addr),
// SRD in SGPRs, OOB (voffset >= num_records) returns 0 with no traffic.
__device__ unsigned llvm_amdgcn_raw_buffer_load_u32(int4v, int, int, int) __asm("llvm.amdgcn.raw.buffer.load.i32");
__device__ uint2v llvm_amdgcn_raw_buffer_load_u32x2(int4v, int, int, int) __asm("llvm.amdgcn.raw.buffer.load.v2i32");

__device__ __forceinline__ int4v make_srd(const void* p, unsigned bytes) {
    unsigned long long a = (unsigned long long)p;
    int4v r;
    r.x = (int)(unsigned)a;
    r.y = (int)((unsigned)(a >> 32) & 0xFFFFu);  // stride=0, flags=0
    r.z = (int)bytes;                            // num_records in bytes
    r.w = 0x00020000;                            // raw dword access
    return r;
}

__device__ __forceinline__ unsigned short f2bf(float f) {
    union { float f; unsigned int u; } v; v.f = f;
    unsigned int u = v.u;
    return (unsigned short)((u + 0x7FFFu + ((u >> 16) & 1u)) >> 16);
}
// packed f32x2 -> bf16x2 (RNE, matches f2bf) in 1 instruction
__device__ __forceinline__ unsigned cvt_pk_bf16(float a, float b) {
    unsigned r;
    asm("v_cvt_pk_bf16_f32 %0, %1, %2" : "=v"(r) : "v"(a), "v"(b));
    return r;
}
// fp8 e4m3 (OCP on gfx950) pack/unpack via HW converts
__device__ __forceinline__ unsigned short pk_fp8(float a, float b) {
    return (unsigned short)(__builtin_amdgcn_cvt_pk_fp8_f32(a, b, 0, false) & 0xFFFF);
}
// accumulate one dword = 4 fp8 into A[0..1] (float2 pairs; v_pk_add_f32)
__device__ __forceinline__ void accum_dw(float2v* A, unsigned w) {
    A[0] += __builtin_amdgcn_cvt_pk_f32_fp8(w, false);
    A[1] += __builtin_amdgcn_cvt_pk_f32_fp8(w, true);
}
__device__ __forceinline__ short8 mk8(unsigned d0, unsigned d1, unsigned d2, unsigned d3) {
    union { unsigned u[4]; short8 s; } v;
    v.u[0] = d0; v.u[1] = d1; v.u[2] = d2; v.u[3] = d3;
    return v.s;
}

// ---------------- merged: bucket partition | x cast | weight prep ----------
// blocks [0,PTBLOCKS): edge partition; [PTBLOCKS,PTBLOCKS+NCASTB): castx;
// last block: weight prep. Independent work overlapped in one launch.

__global__ __launch_bounds__(1024) void k_partx(const int* __restrict__ src,
                                                const int* __restrict__ dst,
                                                int* __restrict__ bucketFill,
                                                unsigned int* __restrict__ pedges,
                                                const float* __restrict__ x,
                                                unsigned short* __restrict__ X8s,
                                                const float* __restrict__ W1l,
                                                const float* __restrict__ W1r,
                                                const float* __restrict__ W2l,
                                                const float* __restrict__ W2r,
                                                const float* __restrict__ Wc,
                                                const float* __restrict__ b2,
                                                const float* __restrict__ bc,
                                                unsigned short* __restrict__ Bt1,
                                                unsigned short* __restrict__ Bt2,
                                                float* __restrict__ bias2) {
    __shared__ int cntL[NBUCK];
    __shared__ int baseL[NBUCK];
    int t = threadIdx.x;
    int bid = blockIdx.x;
    if (bid >= PTBLOCKS) {
        if (bid < PTBLOCKS + NCASTB) {
            // ---- castx: x fp32 -> X8 fp8 rows (32B: 24 real + 8 zero pad) ----
            int gid = (bid - PTBLOCKS) * 1024 + t;
            if (gid >= N_NODES * 16) return;
            int n = gid >> 4, kp = gid & 15;
            if (kp < 12) {
                const float2 v = *(const float2*)(x + n * 24 + kp * 2);
                X8s[n * 16 + kp] = pk_fp8(v.x, v.y);
            } else {
                X8s[n * 16 + kp] = 0;
            }
        } else {
            // ---- weight prep ----
            for (int i = t; i < 64 * 64; i += 1024) {
                int o = i >> 6, k = i & 63;
                float v = (k < 24) ? W1r[o * 24 + k]
                                   : ((k < 48) ? W1l[o * 24 + k - 24] : 0.f);
                Bt1[i] = f2bf(v);
            }
            for (int i = t; i < 64 * 128; i += 1024) {
                int o = i >> 7, k = i & 127;
                float v = (k < 64) ? W2l[o * 64 + k] : W2r[o * 64 + k - 64];
                Bt2[i] = f2bf(v);
            }
            for (int i = t; i < 16 * 128; i += 1024) {
                int c = i >> 7, k = i & 127;
                const float* M = (k < 64) ? W2l : W2r;
                int kk = k & 63;
                float s = 0.f;
                for (int j = 0; j < 64; j++) s += Wc[c * 64 + j] * M[j * 64 + kk];
                Bt2[(64 + c) * 128 + k] = f2bf(s);
            }
            for (int i = t; i < 80; i += 1024) {
                if (i < 64) bias2[i] = b2[i];
                else {
                    int c = i - 64;
                    float s = bc[c];
                    for (int j = 0; j < 64; j++) s += Wc[c * 64 + j] * b2[j];
                    bias2[i] = s;
                }
            }
        }
        return;
    }
    // ---- edge partition ----
    int cbeg = bid * PTCHUNK;
    int d[13], s[13];
#pragma unroll
    for (int k = 0; k < 13; k++) {
        int o = k * 1024 + t;
        bool ok = o < PTCHUNK;
        d[k] = ok ? dst[cbeg + o] : -1;
        s[k] = ok ? src[cbeg + o] : 0;
    }
    for (int i = t; i < NBUCK; i += 1024) cntL[i] = 0;
    __syncthreads();
#pragma unroll
    for (int k = 0; k < 13; k++)
        if (d[k] >= 0) atomicAdd(&cntL[d[k] >> 7], 1);
    __syncthreads();
    for (int i = t; i < NBUCK; i += 1024) {
        int c = cntL[i];
        if (c) baseL[i] = i * CAP + atomicAdd(&bucketFill[i], c);
        cntL[i] = 0;
    }
    __syncthreads();
#pragma unroll
    for (int k = 0; k < 13; k++)
        if (d[k] >= 0) {
            int bk = d[k] >> 7;
            int r = atomicAdd(&cntL[bk], 1);
            pedges[baseL[bk] + r] = ((unsigned int)(d[k] & 127) << 17) | (unsigned int)s[k];
        }
}

// per-bucket finalize: sorted srcs + per-node (beg,end). int LDS atomics only
// (FLOAT LDS atomics are catastrophic on gfx950 — R9: 29x regression)
__global__ __launch_bounds__(1024) void k_bucket(const unsigned int* __restrict__ pedges,
                                                 const int* __restrict__ bucketFill,
                                                 int2* __restrict__ begend,
                                                 int* __restrict__ srcs, int N) {
    __shared__ int ncnt[128];
    __shared__ int sps[128];
    int b = blockIdx.x;
    int t = threadIdx.x;
    int eb0 = b * CAP;
    int m = bucketFill[b];
    unsigned int v[5];
#pragma unroll
    for (int k = 0; k < 5; k++) {
        int o = k * 1024 + t;
        v[k] = (o < m) ? pedges[eb0 + o] : 0xFFFFFFFFu;
    }
    if (t < 128) ncnt[t] = 0;
    __syncthreads();
#pragma unroll
    for (int k = 0; k < 5; k++)
        if (v[k] != 0xFFFFFFFFu) atomicAdd(&ncnt[v[k] >> 17], 1);
    __syncthreads();
    int myc = (t < 128) ? ncnt[t] : 0;
    int val = myc;
    if (t < 128) sps[t] = val;
    __syncthreads();
    for (int off = 1; off < 128; off <<= 1) {
        int vv = (t >= off && t < 128) ? sps[t - off] : 0;
        __syncthreads();
        if (t < 128) { val += vv; sps[t] = val; }
        __syncthreads();
    }
    int mybase = val - myc;
    int node = b * 128 + t;
    if (t < 128 && node < N) {
        int2 be; be.x = eb0 + mybase; be.y = eb0 + mybase + myc;
        begend[node] = be;
    }
    if (t < 128) { sps[t] = mybase; ncnt[t] = 0; }
    // zero slack tail so masked tail gathers read node 0 (cnt+32 <= CAP)
    if (t < 32) srcs[eb0 + m + t] = 0;
    __syncthreads();
#pragma unroll
    for (int k = 0; k < 5; k++)
        if (v[k] != 0xFFFFFFFFu) {
            unsigned int nl = v[k] >> 17;
            int r = atomicAdd(&ncnt[nl], 1);
            srcs[eb0 + sps[nl] + r] = (int)(v[k] & 0x1FFFF);
        }
}

// ---------------- fused layer kernels ----------------
// Block = 128 thr = 2 waves owns a 16-node strip. Phase 1: wave w aggregates
// nodes base+8w..base+8w+7 (r1 per-node loop, identical numerics), means ->
// LDS. Barrier (2-wave groups: minimal degree-imbalance loss; the MFMA's
// 16-row tile forces >=16 nodes per barrier group, so 2 waves x 8 nodes is
// the optimum — r5 4wx4n=68us, r6 16wx1n=82us, r7 2wx8n=64us, r8 1wx16n
// (half the waves)=82us). Phase 2: each wave computes 2 (K1) / 2-3 (K2)
// output tiles; A-fragments built once per wave and reused across tiles.

// K1: agg1 (X8 gather) + gemm1 -> A2 h-zone bf16 + H8 fp8
__global__ __launch_bounds__(128) void k_fuse1(const float* __restrict__ x,
                                               const unsigned int* __restrict__ X8u,
                                               const int2* __restrict__ begend,
                                               const int* __restrict__ srcs,
                                               const unsigned short* __restrict__ Bt1,
                                               const float* __restrict__ b1,
                                               unsigned short* __restrict__ A2s,
                                               unsigned char* __restrict__ H8b) {
    __shared__ unsigned int lds_mean[16][20];   // stride 20 dw: 2-way banks max
    int w = threadIdx.x >> 6;
    int lane = threadIdx.x & 63;
    int base = blockIdx.x * 16;
    int grp = lane >> 3;    // 0..7 edge slot
    int sub = lane & 7;     // dword of 32B row
    const int4v srdX = make_srd(X8u, N_NODES * 32u);
    const int4v srdS = make_srd(srcs, (unsigned)NBUCK * CAP * 4u);
    int suboff = sub * 4;

    // ---- phase 1: wave w aggregates nodes base+8w .. base+8w+7 ----
    for (int i = 0; i < 8; i++) {
        int il = w * 8 + i;
        int2 be = begend[base + il];
        int b = be.x, e = be.y;
        float2v A[2] = {{0.f, 0.f}, {0.f, 0.f}};
        int nfull = (e - b) & ~31;
        int j = b;
        int vo = (b + grp) * 4;
        for (; j < b + nfull; j += 32, vo += 128) {
            int s0 = (int)llvm_amdgcn_raw_buffer_load_u32(srdS, vo, 0, 0);
            int s1 = (int)llvm_amdgcn_raw_buffer_load_u32(srdS, vo + 32, 0, 0);
            int s2 = (int)llvm_amdgcn_raw_buffer_load_u32(srdS, vo + 64, 0, 0);
            int s3 = (int)llvm_amdgcn_raw_buffer_load_u32(srdS, vo + 96, 0, 0);
            unsigned u0 = llvm_amdgcn_raw_buffer_load_u32(srdX, (s0 << 5) + suboff, 0, 0);
            unsigned u1 = llvm_amdgcn_raw_buffer_load_u32(srdX, (s1 << 5) + suboff, 0, 0);
            unsigned u2 = llvm_amdgcn_raw_buffer_load_u32(srdX, (s2 << 5) + suboff, 0, 0);
            unsigned u3 = llvm_amdgcn_raw_buffer_load_u32(srdX, (s3 << 5) + suboff, 0, 0);
            accum_dw(A, u0); accum_dw(A, u1); accum_dw(A, u2); accum_dw(A, u3);
        }
        if (j < e) {
            int j0 = j + grp;
            int s0 = (int)llvm_amdgcn_raw_buffer_load_u32(srdS, vo, 0, 0);
            int s1 = (int)llvm_amdgcn_raw_buffer_load_u32(srdS, vo + 32, 0, 0);
            int s2 = (int)llvm_amdgcn_raw_buffer_load_u32(srdS, vo + 64, 0, 0);
            int s3 = (int)llvm_amdgcn_raw_buffer_load_u32(srdS, vo + 96, 0, 0);
            int o0 = (j0 < e)      ? ((s0 << 5) + suboff) : 0x7FFF0000;
            int o1 = (j0 + 8 < e)  ? ((s1 << 5) + suboff) : 0x7FFF0000;
            int o2 = (j0 + 16 < e) ? ((s2 << 5) + suboff) : 0x7FFF0000;
            int o3 = (j0 + 24 < e) ? ((s3 << 5) + suboff) : 0x7FFF0000;
            unsigned u0 = llvm_amdgcn_raw_buffer_load_u32(srdX, o0, 0, 0);
            unsigned u1 = llvm_amdgcn_raw_buffer_load_u32(srdX, o1, 0, 0);
            unsigned u2 = llvm_amdgcn_raw_buffer_load_u32(srdX, o2, 0, 0);
            unsigned u3 = llvm_amdgcn_raw_buffer_load_u32(srdX, o3, 0, 0);
            accum_dw(A, u0); accum_dw(A, u1); accum_dw(A, u2); accum_dw(A, u3);
        }
#pragma unroll
        for (int mm = 8; mm <= 32; mm <<= 1) {
#pragma unroll
            for (int q = 0; q < 2; q++) {
                float2v t;
                t.x = __shfl_xor(A[q].x, mm, 64);
                t.y = __shfl_xor(A[q].y, mm, 64);
                A[q] += t;
            }
        }
        if (lane < 8) {
            // feats 4*sub..4*sub+3 -> mean dwords 2*sub, 2*sub+1
            float inv = __builtin_amdgcn_rcpf((float)max(e - b, 1));
            lds_mean[il][sub * 2]     = cvt_pk_bf16(A[0].x * inv, A[0].y * inv);
            lds_mean[il][sub * 2 + 1] = cvt_pk_bf16(A[1].x * inv, A[1].y * inv);
        }
    }
    __syncthreads();

    // ---- phase 2: wave w computes tiles 2w, 2w+1 (A-frags built once) ----
    int m = lane & 15, quad = lane >> 4;
    int row = base + m;
    // A-vector (64 shorts): [x bf16 0..23 | mean 0..23 | zeros]
    short8 a0, a1;
    if (quad < 3) {   // shorts quad*8..+7 = x feats quad*8..+7
        const float4* xp = (const float4*)(x + row * 24 + quad * 8);
        float4 v0 = xp[0], v1 = xp[1];
        a0 = mk8(cvt_pk_bf16(v0.x, v0.y), cvt_pk_bf16(v0.z, v0.w),
                 cvt_pk_bf16(v1.x, v1.y), cvt_pk_bf16(v1.z, v1.w));
    } else {          // shorts 24..31 = mean feats 0..7 = lds dwords 0..3
        a0 = *(const short8*)&lds_mean[m][0];
    }
    if (quad == 0)      a1 = *(const short8*)&lds_mean[m][4];  // mean feats 8-15
    else if (quad == 1) a1 = *(const short8*)&lds_mean[m][8];  // mean feats 16-23
    else                a1 = mk8(0u, 0u, 0u, 0u);              // k 48-63 zeros
#pragma unroll
    for (int tt = 0; tt < 2; tt++) {
        int t = w * 2 + tt;
        short8 bf0 = *(const short8*)(Bt1 + (t * 16 + m) * 64 + quad * 8);
        short8 bf1 = *(const short8*)(Bt1 + (t * 16 + m) * 64 + 32 + quad * 8);
        float bias = b1[t * 16 + m];
        float4_ c = {0.f, 0.f, 0.f, 0.f};
        c = __builtin_amdgcn_mfma_f32_16x16x32_bf16(a0, bf0, c, 0, 0, 0);
        c = __builtin_amdgcn_mfma_f32_16x16x32_bf16(a1, bf1, c, 0, 0, 0);
        int col = t * 16 + m;
#pragma unroll
        for (int r = 0; r < 4; r++) {
            int row2 = base + quad * 4 + r;
            float v = fmaxf(c[r] + bias, 0.f);
            A2s[row2 * 128 + 64 + col] = f2bf(v);
            H8b[row2 * 64 + col] =
                (unsigned char)(__builtin_amdgcn_cvt_pk_fp8_f32(v, 0.f, 0, false) & 0xFF);
        }
    }
}

// K2: agg2 (H8 gather) + gemm2 -> embeddings f32 (overwrites A2 rows) + logits
__global__ __launch_bounds__(128) void k_fuse2(const unsigned int* __restrict__ H8u,
                                               const int2* __restrict__ begend,
                                               const int* __restrict__ srcs,
                                               const unsigned short* __restrict__ Bt2,
                                               const float* __restrict__ bias2,
                                               unsigned short* A2s,
                                               float* __restrict__ logits) {
    __shared__ unsigned int lds_h[16][36];      // stride 36 dw: 2-way banks max
    int w = threadIdx.x >> 6;
    int lane = threadIdx.x & 63;
    int base = blockIdx.x * 16;
    int grp = lane >> 3;    // 0..7 edge slot
    int sub = lane & 7;     // 8B chunk of 64B row
    const int4v srdH = make_srd(H8u, N_NODES * 64u);
    const int4v srdS = make_srd(srcs, (unsigned)NBUCK * CAP * 4u);
    int suboff = sub * 8;

    // ---- phase 1: wave w aggregates nodes base+8w .. base+8w+7 ----
    for (int i = 0; i < 8; i++) {
        int il = w * 8 + i;
        int2 be = begend[base + il];
        int b = be.x, e = be.y;
        float2v A[4] = {{0.f, 0.f}, {0.f, 0.f}, {0.f, 0.f}, {0.f, 0.f}};
        int nfull = (e - b) & ~31;
        int j = b;
        int vo = (b + grp) * 4;
        for (; j < b + nfull; j += 32, vo += 128) {
            int s0 = (int)llvm_amdgcn_raw_buffer_load_u32(srdS, vo, 0, 0);
            int s1 = (int)llvm_amdgcn_raw_buffer_load_u32(srdS, vo + 32, 0, 0);
            int s2 = (int)llvm_amdgcn_raw_buffer_load_u32(srdS, vo + 64, 0, 0);
            int s3 = (int)llvm_amdgcn_raw_buffer_load_u32(srdS, vo + 96, 0, 0);
            uint2v u0 = llvm_amdgcn_raw_buffer_load_u32x2(srdH, (s0 << 6) + suboff, 0, 0);
            uint2v u1 = llvm_amdgcn_raw_buffer_load_u32x2(srdH, (s1 << 6) + suboff, 0, 0);
            uint2v u2 = llvm_amdgcn_raw_buffer_load_u32x2(srdH, (s2 << 6) + suboff, 0, 0);
            uint2v u3 = llvm_amdgcn_raw_buffer_load_u32x2(srdH, (s3 << 6) + suboff, 0, 0);
            accum_dw(A, u0.x); accum_dw(A + 2, u0.y);
            accum_dw(A, u1.x); accum_dw(A + 2, u1.y);
            accum_dw(A, u2.x); accum_dw(A + 2, u2.y);
            accum_dw(A, u3.x); accum_dw(A + 2, u3.y);
        }
        if (j < e) {
            int j0 = j + grp;
            int s0 = (int)llvm_amdgcn_raw_buffer_load_u32(srdS, vo, 0, 0);
            int s1 = (int)llvm_amdgcn_raw_buffer_load_u32(srdS, vo + 32, 0, 0);
            int s2 = (int)llvm_amdgcn_raw_buffer_load_u32(srdS, vo + 64, 0, 0);
            int s3 = (int)llvm_amdgcn_raw_buffer_load_u32(srdS, vo + 96, 0, 0);
            int o0 = (j0 < e)      ? ((s0 << 6) + suboff) : 0x7FFF0000;
            int o1 = (j0 + 8 < e)  ? ((s1 << 6) + suboff) : 0x7FFF0000;
            int o2 = (j0 + 16 < e) ? ((s2 << 6) + suboff) : 0x7FFF0000;
            int o3 = (j0 + 24 < e) ? ((s3 << 6) + suboff) : 0x7FFF0000;
            uint2v u0 = llvm_amdgcn_raw_buffer_load_u32x2(srdH, o0, 0, 0);
            uint2v u1 = llvm_amdgcn_raw_buffer_load_u32x2(srdH, o1, 0, 0);
            uint2v u2 = llvm_amdgcn_raw_buffer_load_u32x2(srdH, o2, 0, 0);
            uint2v u3 = llvm_amdgcn_raw_buffer_load_u32x2(srdH, o3, 0, 0);
            accum_dw(A, u0.x); accum_dw(A + 2, u0.y);
            accum_dw(A, u1.x); accum_dw(A + 2, u1.y);
            accum_dw(A, u2.x); accum_dw(A + 2, u2.y);
            accum_dw(A, u3.x); accum_dw(A + 2, u3.y);
        }
#pragma unroll
        for (int mm = 8; mm <= 32; mm <<= 1) {
#pragma unroll
            for (int q = 0; q < 4; q++) {
                float2v t;
                t.x = __shfl_xor(A[q].x, mm, 64);
                t.y = __shfl_xor(A[q].y, mm, 64);
                A[q] += t;
            }
        }
        if (lane < 8) {
            // feats 8*sub..8*sub+7 -> mean dwords 4*sub..4*sub+3
            float inv = __builtin_amdgcn_rcpf((float)max(e - b, 1));
            uint4 o;
            o.x = cvt_pk_bf16(A[0].x * inv, A[0].y * inv);
            o.y = cvt_pk_bf16(A[1].x * inv, A[1].y * inv);
            o.z = cvt_pk_bf16(A[2].x * inv, A[2].y * inv);
            o.w = cvt_pk_bf16(A[3].x * inv, A[3].y * inv);
            *(uint4*)&lds_h[il][sub * 4] = o;
        }
    }
    __syncthreads();   // barrier 1: all means in LDS

    // ---- phase 2: wave 0 -> tiles {0,1}; wave 1 -> tiles {2,3,logits} ----
    int m = lane & 15, quad = lane >> 4;
    int row = base + m;
    // h-zone A-frags (global, about to be overwritten) — load BEFORE barrier 2
    short8 a2 = *(const short8*)(A2s + row * 128 + 64 + quad * 8);
    short8 a3 = *(const short8*)(A2s + row * 128 + 96 + quad * 8);
    // barrier 2: all h-zone reads complete before embeddings overwrite rows
    __syncthreads();
    short8 a0 = *(const short8*)&lds_h[m][quad * 4];
    short8 a1 = *(const short8*)&lds_h[m][16 + quad * 4];
    int ntile = (w == 0) ? 2 : 3;
#pragma unroll
    for (int tt = 0; tt < 3; tt++) {
        if (tt >= ntile) break;
        int t = (w == 0) ? tt : 2 + tt;          // w1: 2,3,4(logits)
        int trow = ((t < 4) ? t * 16 : 64) + m;
        short8 bf0 = *(const short8*)(Bt2 + trow * 128 + quad * 8);
        short8 bf1 = *(const short8*)(Bt2 + trow * 128 + 32 + quad * 8);
        short8 bf2 = *(const short8*)(Bt2 + trow * 128 + 64 + quad * 8);
        short8 bf3 = *(const short8*)(Bt2 + trow * 128 + 96 + quad * 8);
        float bias = bias2[trow];
        float4_ c = {0.f, 0.f, 0.f, 0.f};
        c = __builtin_amdgcn_mfma_f32_16x16x32_bf16(a0, bf0, c, 0, 0, 0);
        c = __builtin_amdgcn_mfma_f32_16x16x32_bf16(a1, bf1, c, 0, 0, 0);
        c = __builtin_amdgcn_mfma_f32_16x16x32_bf16(a2, bf2, c, 0, 0, 0);
        c = __builtin_amdgcn_mfma_f32_16x16x32_bf16(a3, bf3, c, 0, 0, 0);
        if (t < 4) {
            float* embp = (float*)A2s;
            int col = t * 16 + m;
#pragma unroll
            for (int r = 0; r < 4; r++) {
                int row2 = base + quad * 4 + r;
                embp[row2 * 64 + col] = c[r] + bias;
            }
        } else {
#pragma unroll
            for (int r = 0; r < 4; r++) {
                int row2 = base + quad * 4 + r;
                logits[row2 * 16 + m] = c[r] + bias;
            }
        }
    }
}

// ---------------- launch ----------------

extern "C" void kernel_launch(void* const* d_in, const int* in_sizes, int n_in,
                              void* d_out, int out_size, void* d_ws, size_t ws_size,
                              hipStream_t stream) {
    const float* x = (const float*)d_in[0];
    const int* edge = (const int*)d_in[1];
    const int* srcIdx = edge;
    const int* dstIdx = edge + N_EDGES;
    const float* W1l = (const float*)d_in[2];
    const float* b1  = (const float*)d_in[3];
    const float* W1r = (const float*)d_in[4];
    const float* W2l = (const float*)d_in[5];
    const float* b2  = (const float*)d_in[6];
    const float* W2r = (const float*)d_in[7];
    const float* Wc  = (const float*)d_in[8];
    const float* bc  = (const float*)d_in[9];

    float* logits = (float*)d_out;
    unsigned short* A2s = (unsigned short*)((float*)d_out + (size_t)N_NODES * N_CLASSES);

    char* w = (char*)d_ws;
    auto carve = [&](size_t bytes) {
        char* p = w;
        w += (bytes + 255) & ~(size_t)255;
        return p;
    };
    int2* begend         = (int2*)carve((size_t)N_NODES * sizeof(int2));
    int* srcs            = (int*)carve((size_t)NBUCK * CAP * sizeof(int));
    unsigned int* pedges = (unsigned int*)carve((size_t)NBUCK * CAP * sizeof(unsigned int));
    unsigned short* X8s  = (unsigned short*)carve((size_t)N_NODES * 32);   // fp8 x, 32B rows
    unsigned char* H8b   = (unsigned char*)carve((size_t)N_NODES * 64);    // fp8 h, 64B rows
    int* bucketFill      = (int*)carve(NBUCK * sizeof(int));
    unsigned short* Bt1  = (unsigned short*)carve(64 * 64 * sizeof(unsigned short));
    unsigned short* Bt2  = (unsigned short*)carve(80 * 128 * sizeof(unsigned short));
    float* bias2         = (float*)carve(80 * sizeof(float));

    unsigned int* X8u = (unsigned int*)X8s;
    unsigned int* H8u = (unsigned int*)H8b;

    hipMemsetAsync(bucketFill, 0, NBUCK * sizeof(int), stream);
    k_partx<<<PTBLOCKS + NCASTB + 1, 1024, 0, stream>>>(
        srcIdx, dstIdx, bucketFill, pedges, x, X8s,
        W1l, W1r, W2l, W2r, Wc, b2, bc, Bt1, Bt2, bias2);
    k_bucket<<<NBUCK, 1024, 0, stream>>>(pedges, bucketFill, begend, srcs, N_NODES);

    int fgrid = N_NODES / 16;   // 6250 strips
    k_fuse1<<<fgrid, 128, 0, stream>>>(x, X8u, begend, srcs, Bt1, b1, A2s, H8b);
    k_fuse2<<<fgrid, 128, 0, stream>>>(H8u, begend, srcs, Bt2, bias2, A2s, logits);
}